// Round 11
// baseline (148.689 us; speedup 1.0000x reference)
//
#include <hip/hip_runtime.h>
#include <hip/hip_bf16.h>

#define BQ   16
#define BK2  32     // 2B
#define SEQ  256
#define HD   768

typedef __attribute__((ext_vector_type(8))) short bf16x8;
typedef __attribute__((ext_vector_type(4))) float f32x4;

__device__ __forceinline__ void glds16(const unsigned short* g, unsigned short* l) {
    __builtin_amdgcn_global_load_lds(
        (const __attribute__((address_space(1))) unsigned int*)g,
        (__attribute__((address_space(3))) unsigned int*)l, 16, 0, 0);
}

// branch-free RNE fp32->bf16, packed two at a time
__device__ __forceinline__ unsigned int pack2_bf16(float a, float b) {
    unsigned ua = __float_as_uint(a), ub = __float_as_uint(b);
    ua += 0x7FFFu + ((ua >> 16) & 1u);
    ub += 0x7FFFu + ((ub >> 16) & 1u);
    return (ua >> 16) | (ub & 0xFFFF0000u);
}

// ---------------- Phase 1: l2-normalize -> bf16, + zero out, + compaction --
// Blocks 0..3071: 4 rows each (wave per row) of fp32 -> bf16 l2-norm.
// Blocks 3072..3083: 4 mask rows each (wave per row) -> compact index lists
// (ballot prefix-sum, ascending, padded with 0).  One dispatch total.
__global__ __launch_bounds__(256) void norm_kernel(
    const float* __restrict__ q, const float* __restrict__ k,
    unsigned short* __restrict__ qn, unsigned short* __restrict__ kn,
    const int* __restrict__ q_mask, const int* __restrict__ k_mask,
    int* __restrict__ sidx, int* __restrict__ cnts,
    int* __restrict__ tidx, int* __restrict__ cntt,
    float* __restrict__ out)
{
    const int w    = threadIdx.x >> 6;
    const int lane = threadIdx.x & 63;

    if (blockIdx.x >= 3072) {                    // ---- compaction tail ----
        const int row48 = (blockIdx.x - 3072) * 4 + w;   // 0..47
        const bool isq = row48 < BQ;
        const int* m = isq ? q_mask + row48 * SEQ : k_mask + (row48 - BQ) * SEQ;
        int* idx     = isq ? sidx + row48 * SEQ  : tidx + (row48 - BQ) * SEQ;
        int base = 0;
#pragma unroll
        for (int c = 0; c < 4; ++c) {
            int v = (m[c * 64 + lane] != 0);
            unsigned long long b = __ballot(v);
            int pre = __popcll(b & ((1ull << lane) - 1ull));
            if (v) idx[base + pre] = c * 64 + lane;
            base += (int)__popcll(b);
        }
        for (int p = base + lane; p < SEQ; p += 64) idx[p] = 0;   // pad
        if (lane == 0) { if (isq) cnts[row48] = base; else cntt[row48 - BQ] = base; }
        return;
    }

    if (blockIdx.x == 0 && threadIdx.x < 256) {  // zero out for li's atomics
        out[threadIdx.x] = 0.f; out[threadIdx.x + 256] = 0.f;
    }
    int row  = blockIdx.x * 4 + w;
    const int NQ = BQ * SEQ;
    const float* src = (row < NQ) ? q + (size_t)row * HD
                                  : k + (size_t)(row - NQ) * HD;
    unsigned int* dst = (unsigned int*)((row < NQ) ? qn + (size_t)row * HD
                                                   : kn + (size_t)(row - NQ) * HD);
    float4 v[3];
    float ss = 0.f;
#pragma unroll
    for (int c = 0; c < 3; ++c) {
        v[c] = ((const float4*)src)[lane + 64 * c];
        ss += v[c].x * v[c].x + v[c].y * v[c].y + v[c].z * v[c].z + v[c].w * v[c].w;
    }
#pragma unroll
    for (int m = 1; m < 64; m <<= 1) ss += __shfl_xor(ss, m, 64);
    float inv = rsqrtf(fmaxf(ss, 1e-24f));
#pragma unroll
    for (int c = 0; c < 3; ++c) {
        uint2 o = make_uint2(pack2_bf16(v[c].x * inv, v[c].y * inv),
                             pack2_bf16(v[c].z * inv, v[c].w * inv));
        ((uint2*)dst)[lane + 64 * c] = o;
    }
}

// ---------------- Phase 2: block = (j, i, s-chunk), 128 compact-s x 256 t --
// r10's proven 8-wave geometry + 16-granular tile gating:
//  - block-level: early-exit s-chunks beyond cs; skip A-group-1 staging when
//    csrem <= 64; B staging only for c < ntg (64-granular).
//  - wave-level: rmact/cnact = active 16-tiles in s/t; per ks one uniform
//    branch: full 4x4 path (branch-free) or guarded path (static unroll).
// Valid (s,t) always in active tiles; invalid rows/slots nulled by masks.
__global__ __launch_bounds__(512, 2) void li_kernel(
    const unsigned short* __restrict__ qn, const unsigned short* __restrict__ kn,
    const float* __restrict__ g_ls, const float* __restrict__ g_ar,
    const int* __restrict__ sidx, const int* __restrict__ cnts,
    const int* __restrict__ tidx, const int* __restrict__ cntt,
    float* __restrict__ out)
{
    const int j  = blockIdx.x, i = blockIdx.y, chs = blockIdx.z;
    const int cs = cnts[i], ct = cntt[j];
    if (chs * 128 >= cs || ct == 0) return;   // block-uniform exit
    int csrem = cs - chs * 128; if (csrem > 128) csrem = 128;
    const int ns16 = (csrem + 15) >> 4;       // active s 16-tiles, 1..8
    const int nt16 = (ct + 15) >> 4;          // active t 16-tiles, 1..16
    const int ntg  = (nt16 + 3) >> 2;         // active t 64-groups, 1..4

    const int tid  = threadIdx.x;
    const int w    = tid >> 6, lane = tid & 63;
    const int ln   = lane & 15, lg = lane >> 4;
    const int wsd  = w >> 2, wt = w & 3;      // wave = (s-half, t-quarter)

    int rmact = ns16 - wsd * 4; rmact = rmact < 0 ? 0 : (rmact > 4 ? 4 : rmact);
    int cnact = nt16 - wt * 4;  cnact = cnact < 0 ? 0 : (cnact > 4 ? 4 : cnact);
    const bool full = (rmact == 4) & (cnact == 4);
    const bool wactive = (rmact > 0) & (cnact > 0);

    __shared__ __align__(16) unsigned short As[128 * 64];  // 16 KB, swizzled
    __shared__ __align__(16) unsigned short Bs[256 * 64];  // 32 KB, swizzled
    __shared__ float w2[SEQ];      // scale * exp(-alpha*d) * log2(e)
    __shared__ int   sor[128], tor[SEQ];     // original s/t of compact slots
    __shared__ float red[8];

    float a0 = g_ar[0];
    float alpha = (a0 > 0.f) ? a0 : 0.01f * a0;            // leaky_relu
    float scale = __expf(g_ls[0]) * 1.4426950408889634f;   // fold log2(e)
    if (tid < 256) {
        w2[tid]  = scale * __expf(-alpha * (float)tid);
        tor[tid] = tidx[j * SEQ + tid];
    } else if (tid < 384) {
        sor[tid - 256] = sidx[i * SEQ + chs * 128 + (tid - 256)];
    }

    // glds staging (r0 involution): lane covers row (base + lane>>3),
    // LDS chunk slot (lane&7), pre-swizzled source chunk (lane&7)^(row&7).
    const int rl  = lane >> 3;
    const int gch = (lane & 7) ^ rl;
    const int ia0 = sidx[i * SEQ + chs * 128 + w * 8 + rl];        // A rows 0..63
    const int ia1 = sidx[i * SEQ + chs * 128 + 64 + w * 8 + rl];   // A rows 64..127
    int ib[4];
#pragma unroll
    for (int c = 0; c < 4; ++c)
        ib[c] = tidx[j * SEQ + c * 64 + w * 8 + rl];               // B rows c*64+..
    const unsigned short* qb = qn + (size_t)i * SEQ * HD + gch * 8;
    const unsigned short* kb = kn + (size_t)j * SEQ * HD + gch * 8;
    unsigned short* al = As + (w * 8) * 64;
    unsigned short* bl = Bs + (w * 8) * 64;
    const bool stA1 = (csrem > 64);           // block-uniform

    f32x4 acc[4][4];
    const f32x4 zero4 = {0.f, 0.f, 0.f, 0.f};
#pragma unroll
    for (int a = 0; a < 4; ++a)
#pragma unroll
        for (int b = 0; b < 4; ++b) acc[a][b] = zero4;

    for (int kk = 0; kk < HD; kk += 64) {
        __syncthreads();                       // prev stage consumed
        glds16(qb + (size_t)ia0 * HD + kk, al);
        if (stA1) glds16(qb + (size_t)ia1 * HD + kk, al + 64 * 64);
#pragma unroll
        for (int c = 0; c < 4; ++c)            // only active t-groups staged
            if (c < ntg) glds16(kb + (size_t)ib[c] * HD + kk, bl + c * (64 * 64));
        __syncthreads();                       // vmcnt drained before barrier
        const bf16x8* A8 = (const bf16x8*)As;
        const bf16x8* B8 = (const bf16x8*)Bs;
#pragma unroll
        for (int ks = 0; ks < 2; ++ks) {
            const int ch = (ks * 4 + lg) ^ (ln & 7);   // unswizzle
            bf16x8 af[4], bfr[4];
            if (full) {                        // common case: branch-free 4x4
#pragma unroll
                for (int rm = 0; rm < 4; ++rm)
                    af[rm] = A8[(wsd * 64 + rm * 16 + ln) * 8 + ch];
#pragma unroll
                for (int cn = 0; cn < 4; ++cn)
                    bfr[cn] = B8[(wt * 64 + cn * 16 + ln) * 8 + ch];
#pragma unroll
                for (int rm = 0; rm < 4; ++rm)
#pragma unroll
                    for (int cn = 0; cn < 4; ++cn)
                        acc[rm][cn] = __builtin_amdgcn_mfma_f32_16x16x32_bf16(
                            af[rm], bfr[cn], acc[rm][cn], 0, 0, 0);
            } else if (wactive) {              // partial tiles: static guards
#pragma unroll
                for (int rm = 0; rm < 4; ++rm)
                    if (rm < rmact) af[rm] = A8[(wsd * 64 + rm * 16 + ln) * 8 + ch];
#pragma unroll
                for (int cn = 0; cn < 4; ++cn)
                    if (cn < cnact) bfr[cn] = B8[(wt * 64 + cn * 16 + ln) * 8 + ch];
#pragma unroll
                for (int rm = 0; rm < 4; ++rm)
#pragma unroll
                    for (int cn = 0; cn < 4; ++cn)
                        if (rm < rmact && cn < cnact)
                            acc[rm][cn] = __builtin_amdgcn_mfma_f32_16x16x32_bf16(
                                af[rm], bfr[cn], acc[rm][cn], 0, 0, 0);
            }
        }
    }

    // ---------------- slim epilogue (r10, wactive-gated) -------------------
    __syncthreads();                    // all MFMA LDS reads done; reuse Bs
    float* zs  = (float*)Bs;            // [16][133] Z partials
    float* wsc = zs + 16 * 133;         // [16][133] W partials

    int   to[4];
    float kv[4];
#pragma unroll
    for (int cn = 0; cn < 4; ++cn) {
        int slot = wt * 64 + cn * 16 + ln;
        to[cn] = tor[slot];
        kv[cn] = (slot < ct) ? 1.f : 0.f;
    }

#pragma unroll
    for (int rm = 0; rm < 4; ++rm)
#pragma unroll
        for (int r = 0; r < 4; ++r) {
            int srow = wsd * 64 + rm * 16 + lg * 4 + r;   // compact s 0..127
            float ze = 0.f, we = 0.f;
            if (wactive) {
                int so = sor[srow];
#pragma unroll
                for (int cn = 0; cn < 4; ++cn) {
                    float sim = acc[rm][cn][r];
                    int d = so - to[cn]; d = (d < 0) ? -d : d;
                    float e = kv[cn] * __builtin_exp2f(sim * w2[d]);
                    ze += e;
                    we = fmaf(e, sim, we);
                }
            }
            ze += __shfl_xor(ze, 1, 64);  we += __shfl_xor(we, 1, 64);
            ze += __shfl_xor(ze, 2, 64);  we += __shfl_xor(we, 2, 64);
            if ((ln & 3) == 0) {
                int zrow = wt * 4 + (ln >> 2);            // 0..15
                zs [zrow * 133 + srow] = ze;
                wsc[zrow * 133 + srow] = we;
            }
        }
    __syncthreads();

    float part = 0.f;
    if (tid < 128) {
        float Z = 0.f, W = 0.f;
#pragma unroll
        for (int c = 0; c < 16; ++c) {
            Z += zs [c * 133 + tid];
            W += wsc[c * 133 + tid];
        }
        float pt = (Z > 0.f) ? (W / Z) : 0.f;
        part = (chs * 128 + tid < cs) ? pt : 0.f;   // q-mask == slot validity
    }
#pragma unroll
    for (int m = 1; m < 64; m <<= 1) part += __shfl_xor(part, m, 64);
    if (lane == 0) red[w] = part;
    __syncthreads();
    if (tid == 0) {
        float tot = red[0] + red[1] + red[2] + red[3]
                  + red[4] + red[5] + red[6] + red[7];
        atomicAdd(&out[i * BK2 + j], tot);
    }
}

extern "C" void kernel_launch(void* const* d_in, const int* in_sizes, int n_in,
                              void* d_out, int out_size, void* d_ws, size_t ws_size,
                              hipStream_t stream) {
    const float* q  = (const float*)d_in[0];   // [16,256,768] f32
    const float* k  = (const float*)d_in[1];   // [32,256,768] f32
    const float* ls = (const float*)d_in[2];   // scalar
    const float* ar = (const float*)d_in[3];   // scalar
    const int* qm   = (const int*)d_in[4];     // [16,256]
    const int* km   = (const int*)d_in[5];     // [32,256]
    float* out      = (float*)d_out;           // [16,32] f32

    unsigned short* qn = (unsigned short*)d_ws;            // 16*256*768 bf16
    unsigned short* kn = qn + (size_t)BQ * SEQ * HD;       // 32*256*768 bf16
    int* sidx = (int*)(kn + (size_t)BK2 * SEQ * HD);       // [16][256]
    int* cnts = sidx + BQ * SEQ;                           // [16]
    int* tidx = cnts + BQ;                                 // [32][256]
    int* cntt = tidx + BK2 * SEQ;                          // [32]

    norm_kernel<<<(BQ + BK2) * SEQ / 4 + 12, 256, 0, stream>>>(
        q, k, qn, kn, qm, km, sidx, cnts, tidx, cntt, (float*)d_out);
    li_kernel<<<dim3(BK2, BQ, 2), 512, 0, stream>>>(qn, kn, ls, ar,
                                                    sidx, cnts, tidx, cntt,
                                                    (float*)d_out);
}

// Round 12
// 127.658 us; speedup vs baseline: 1.1647x; 1.1647x over previous
//
#include <hip/hip_runtime.h>
#include <hip/hip_bf16.h>

#define BQ   16
#define BK2  32     // 2B
#define SEQ  256
#define HD   768

typedef __attribute__((ext_vector_type(8))) short bf16x8;
typedef __attribute__((ext_vector_type(4))) float f32x4;

__device__ __forceinline__ void glds16(const unsigned short* g, unsigned short* l) {
    __builtin_amdgcn_global_load_lds(
        (const __attribute__((address_space(1))) unsigned int*)g,
        (__attribute__((address_space(3))) unsigned int*)l, 16, 0, 0);
}

// branch-free RNE fp32->bf16, packed two at a time
__device__ __forceinline__ unsigned int pack2_bf16(float a, float b) {
    unsigned ua = __float_as_uint(a), ub = __float_as_uint(b);
    ua += 0x7FFFu + ((ua >> 16) & 1u);
    ub += 0x7FFFu + ((ub >> 16) & 1u);
    return (ua >> 16) | (ub & 0xFFFF0000u);
}

// ---------------- Phase 1: l2-normalize -> bf16, + zero out, + compaction --
// Blocks 0..3071: 4 rows each (wave per row) of fp32 -> bf16 l2-norm.
// Blocks 3072..3083: 4 mask rows each (wave per row) -> compact index lists
// (ballot prefix-sum, ascending, padded with 0).  One dispatch total.
// [verified r11]
__global__ __launch_bounds__(256) void norm_kernel(
    const float* __restrict__ q, const float* __restrict__ k,
    unsigned short* __restrict__ qn, unsigned short* __restrict__ kn,
    const int* __restrict__ q_mask, const int* __restrict__ k_mask,
    int* __restrict__ sidx, int* __restrict__ cnts,
    int* __restrict__ tidx, int* __restrict__ cntt,
    float* __restrict__ out)
{
    const int w    = threadIdx.x >> 6;
    const int lane = threadIdx.x & 63;

    if (blockIdx.x >= 3072) {                    // ---- compaction tail ----
        const int row48 = (blockIdx.x - 3072) * 4 + w;   // 0..47
        const bool isq = row48 < BQ;
        const int* m = isq ? q_mask + row48 * SEQ : k_mask + (row48 - BQ) * SEQ;
        int* idx     = isq ? sidx + row48 * SEQ  : tidx + (row48 - BQ) * SEQ;
        int base = 0;
#pragma unroll
        for (int c = 0; c < 4; ++c) {
            int v = (m[c * 64 + lane] != 0);
            unsigned long long b = __ballot(v);
            int pre = __popcll(b & ((1ull << lane) - 1ull));
            if (v) idx[base + pre] = c * 64 + lane;
            base += (int)__popcll(b);
        }
        for (int p = base + lane; p < SEQ; p += 64) idx[p] = 0;   // pad
        if (lane == 0) { if (isq) cnts[row48] = base; else cntt[row48 - BQ] = base; }
        return;
    }

    if (blockIdx.x == 0 && threadIdx.x < 256) {  // zero out for li's atomics
        out[threadIdx.x] = 0.f; out[threadIdx.x + 256] = 0.f;
    }
    int row  = blockIdx.x * 4 + w;
    const int NQ = BQ * SEQ;
    const float* src = (row < NQ) ? q + (size_t)row * HD
                                  : k + (size_t)(row - NQ) * HD;
    unsigned int* dst = (unsigned int*)((row < NQ) ? qn + (size_t)row * HD
                                                   : kn + (size_t)(row - NQ) * HD);
    float4 v[3];
    float ss = 0.f;
#pragma unroll
    for (int c = 0; c < 3; ++c) {
        v[c] = ((const float4*)src)[lane + 64 * c];
        ss += v[c].x * v[c].x + v[c].y * v[c].y + v[c].z * v[c].z + v[c].w * v[c].w;
    }
#pragma unroll
    for (int m = 1; m < 64; m <<= 1) ss += __shfl_xor(ss, m, 64);
    float inv = rsqrtf(fmaxf(ss, 1e-24f));
#pragma unroll
    for (int c = 0; c < 3; ++c) {
        uint2 o = make_uint2(pack2_bf16(v[c].x * inv, v[c].y * inv),
                             pack2_bf16(v[c].z * inv, v[c].w * inv));
        ((uint2*)dst)[lane + 64 * c] = o;
    }
}

// ---------------- Phase 2: block = (j, i, s-chunk), 128 compact-s x 256 t --
// r10's proven kernel VERBATIM (47.6 us) + ONE block-uniform addition:
// skip A-group-1 staging when csrem <= 64 (stA1). No branches inside the
// fragment/MFMA path (r11's 16-granular gating regressed 60% -- codegen).
//  - hard win: early-exit s-chunks beyond cs (~26% fewer blocks)
//  - soft win: t-groups >= ntg = ceil(ct/64) skip staging/MFMA/exp
//    (wave-uniform; idle waves free issue slots for co-resident blocks)
__global__ __launch_bounds__(512, 2) void li_kernel(
    const unsigned short* __restrict__ qn, const unsigned short* __restrict__ kn,
    const float* __restrict__ g_ls, const float* __restrict__ g_ar,
    const int* __restrict__ sidx, const int* __restrict__ cnts,
    const int* __restrict__ tidx, const int* __restrict__ cntt,
    float* __restrict__ out)
{
    const int j  = blockIdx.x, i = blockIdx.y, chs = blockIdx.z;
    const int cs = cnts[i], ct = cntt[j];
    if (chs * 128 >= cs || ct == 0) return;   // block-uniform exit
    int csrem = cs - chs * 128; if (csrem > 128) csrem = 128;
    const int ntg = (ct + 63) >> 6;           // active t-groups, 1..4
    const bool stA1 = (csrem > 64);           // block-uniform A-group-1 gate

    const int tid  = threadIdx.x;
    const int w    = tid >> 6, lane = tid & 63;
    const int ln   = lane & 15, lg = lane >> 4;
    const int wsd  = w >> 2, wt = w & 3;      // wave = (s-half, t-quarter)

    __shared__ __align__(16) unsigned short As[128 * 64];  // 16 KB, swizzled
    __shared__ __align__(16) unsigned short Bs[256 * 64];  // 32 KB, swizzled
    __shared__ float w2[SEQ];      // scale * exp(-alpha*d) * log2(e)
    __shared__ int   sor[128], tor[SEQ];     // original s/t of compact slots
    __shared__ float red[8];

    float a0 = g_ar[0];
    float alpha = (a0 > 0.f) ? a0 : 0.01f * a0;            // leaky_relu
    float scale = __expf(g_ls[0]) * 1.4426950408889634f;   // fold log2(e)
    if (tid < 256) {
        w2[tid]  = scale * __expf(-alpha * (float)tid);
        tor[tid] = tidx[j * SEQ + tid];
    } else if (tid < 384) {
        sor[tid - 256] = sidx[i * SEQ + chs * 128 + (tid - 256)];
    }

    // glds staging (r0 involution): lane covers row (base + lane>>3),
    // LDS chunk slot (lane&7), pre-swizzled source chunk (lane&7)^(row&7).
    const int rl  = lane >> 3;
    const int gch = (lane & 7) ^ rl;
    const int ia0 = sidx[i * SEQ + chs * 128 + w * 8 + rl];        // A rows 0..63
    const int ia1 = sidx[i * SEQ + chs * 128 + 64 + w * 8 + rl];   // A rows 64..127
    int ib[4];
#pragma unroll
    for (int c = 0; c < 4; ++c)
        ib[c] = tidx[j * SEQ + c * 64 + w * 8 + rl];               // B rows c*64+..
    const unsigned short* qb = qn + (size_t)i * SEQ * HD + gch * 8;
    const unsigned short* kb = kn + (size_t)j * SEQ * HD + gch * 8;
    unsigned short* al = As + (w * 8) * 64;
    unsigned short* bl = Bs + (w * 8) * 64;

    f32x4 acc[4][4];
    const f32x4 zero4 = {0.f, 0.f, 0.f, 0.f};
#pragma unroll
    for (int a = 0; a < 4; ++a)
#pragma unroll
        for (int b = 0; b < 4; ++b) acc[a][b] = zero4;

    const bool wact = (wt < ntg);             // wave-uniform t-activity

    for (int kk = 0; kk < HD; kk += 64) {
        __syncthreads();                       // prev stage consumed
        glds16(qb + (size_t)ia0 * HD + kk, al);
        if (stA1) glds16(qb + (size_t)ia1 * HD + kk, al + 64 * 64);
#pragma unroll
        for (int c = 0; c < 4; ++c)            // only active t-groups staged
            if (c < ntg) glds16(kb + (size_t)ib[c] * HD + kk, bl + c * (64 * 64));
        __syncthreads();                       // vmcnt drained before barrier
        if (wact) {
            const bf16x8* A8 = (const bf16x8*)As;
            const bf16x8* B8 = (const bf16x8*)Bs;
#pragma unroll
            for (int ks = 0; ks < 2; ++ks) {
                const int ch = (ks * 4 + lg) ^ (ln & 7);   // unswizzle
                bf16x8 af[4], bfr[4];
#pragma unroll
                for (int rm = 0; rm < 4; ++rm)
                    af[rm] = A8[(wsd * 64 + rm * 16 + ln) * 8 + ch];
#pragma unroll
                for (int cn = 0; cn < 4; ++cn)
                    bfr[cn] = B8[(wt * 64 + cn * 16 + ln) * 8 + ch];
#pragma unroll
                for (int rm = 0; rm < 4; ++rm)
#pragma unroll
                    for (int cn = 0; cn < 4; ++cn)
                        acc[rm][cn] = __builtin_amdgcn_mfma_f32_16x16x32_bf16(
                            af[rm], bfr[cn], acc[rm][cn], 0, 0, 0);
            }
        }
    }

    // ---------------- slim epilogue (r10) ----------------------------------
    __syncthreads();                    // all MFMA LDS reads done; reuse Bs
    float* zs  = (float*)Bs;            // [16][133] Z partials
    float* wsc = zs + 16 * 133;         // [16][133] W partials

    int   to[4];
    float kv[4];
#pragma unroll
    for (int cn = 0; cn < 4; ++cn) {
        int slot = wt * 64 + cn * 16 + ln;
        to[cn] = tor[slot];
        kv[cn] = (slot < ct) ? 1.f : 0.f;
    }

#pragma unroll
    for (int rm = 0; rm < 4; ++rm)
#pragma unroll
        for (int r = 0; r < 4; ++r) {
            int srow = wsd * 64 + rm * 16 + lg * 4 + r;   // compact s 0..127
            float ze = 0.f, we = 0.f;
            if (wact) {
                int so = sor[srow];
#pragma unroll
                for (int cn = 0; cn < 4; ++cn) {
                    float sim = acc[rm][cn][r];
                    int d = so - to[cn]; d = (d < 0) ? -d : d;
                    float e = kv[cn] * __builtin_exp2f(sim * w2[d]);
                    ze += e;
                    we = fmaf(e, sim, we);
                }
            }
            ze += __shfl_xor(ze, 1, 64);  we += __shfl_xor(we, 1, 64);
            ze += __shfl_xor(ze, 2, 64);  we += __shfl_xor(we, 2, 64);
            if ((ln & 3) == 0) {
                int zrow = wt * 4 + (ln >> 2);            // 0..15
                zs [zrow * 133 + srow] = ze;
                wsc[zrow * 133 + srow] = we;
            }
        }
    __syncthreads();

    float part = 0.f;
    if (tid < 128) {
        float Z = 0.f, W = 0.f;
#pragma unroll
        for (int c = 0; c < 16; ++c) {
            Z += zs [c * 133 + tid];
            W += wsc[c * 133 + tid];
        }
        float pt = (Z > 0.f) ? (W / Z) : 0.f;
        part = (chs * 128 + tid < cs) ? pt : 0.f;   // q-mask == slot validity
    }
#pragma unroll
    for (int m = 1; m < 64; m <<= 1) part += __shfl_xor(part, m, 64);
    if (lane == 0) red[w] = part;
    __syncthreads();
    if (tid == 0) {
        float tot = red[0] + red[1] + red[2] + red[3]
                  + red[4] + red[5] + red[6] + red[7];
        atomicAdd(&out[i * BK2 + j], tot);
    }
}

extern "C" void kernel_launch(void* const* d_in, const int* in_sizes, int n_in,
                              void* d_out, int out_size, void* d_ws, size_t ws_size,
                              hipStream_t stream) {
    const float* q  = (const float*)d_in[0];   // [16,256,768] f32
    const float* k  = (const float*)d_in[1];   // [32,256,768] f32
    const float* ls = (const float*)d_in[2];   // scalar
    const float* ar = (const float*)d_in[3];   // scalar
    const int* qm   = (const int*)d_in[4];     // [16,256]
    const int* km   = (const int*)d_in[5];     // [32,256]
    float* out      = (float*)d_out;           // [16,32] f32

    unsigned short* qn = (unsigned short*)d_ws;            // 16*256*768 bf16
    unsigned short* kn = qn + (size_t)BQ * SEQ * HD;       // 32*256*768 bf16
    int* sidx = (int*)(kn + (size_t)BK2 * SEQ * HD);       // [16][256]
    int* cnts = sidx + BQ * SEQ;                           // [16]
    int* tidx = cnts + BQ;                                 // [32][256]
    int* cntt = tidx + BK2 * SEQ;                          // [32]

    norm_kernel<<<(BQ + BK2) * SEQ / 4 + 12, 256, 0, stream>>>(
        q, k, qn, kn, qm, km, sidx, cnts, tidx, cntt, (float*)d_out);
    li_kernel<<<dim3(BK2, BQ, 2), 512, 0, stream>>>(qn, kn, ls, ar,
                                                    sidx, cnts, tidx, cntt,
                                                    (float*)d_out);
}

// Round 13
// 123.171 us; speedup vs baseline: 1.2072x; 1.0364x over previous
//
#include <hip/hip_runtime.h>
#include <hip/hip_bf16.h>

#define BQ   16
#define BK2  32     // 2B
#define SEQ  256
#define HD   768

typedef __attribute__((ext_vector_type(8))) short bf16x8;
typedef __attribute__((ext_vector_type(4))) float f32x4;

__device__ __forceinline__ void glds16(const unsigned short* g, unsigned short* l) {
    __builtin_amdgcn_global_load_lds(
        (const __attribute__((address_space(1))) unsigned int*)g,
        (__attribute__((address_space(3))) unsigned int*)l, 16, 0, 0);
}

// branch-free RNE fp32->bf16, packed two at a time
__device__ __forceinline__ unsigned int pack2_bf16(float a, float b) {
    unsigned ua = __float_as_uint(a), ub = __float_as_uint(b);
    ua += 0x7FFFu + ((ua >> 16) & 1u);
    ub += 0x7FFFu + ((ub >> 16) & 1u);
    return (ua >> 16) | (ub & 0xFFFF0000u);
}

// ---------------- Phase 1: l2-normalize -> bf16, + zero out, + compaction --
// Blocks 0..3071: 4 rows each (wave per row); MASKED ROWS SKIPPED (li only
// reads rows referenced by the compact index lists, which are all valid).
// Blocks 3072..3083: compaction tail -- pads idx[cnt..256) with the FIRST
// VALID index (not 0), so padded slots always point at normalized rows.
__global__ __launch_bounds__(256) void norm_kernel(
    const float* __restrict__ q, const float* __restrict__ k,
    unsigned short* __restrict__ qn, unsigned short* __restrict__ kn,
    const int* __restrict__ q_mask, const int* __restrict__ k_mask,
    int* __restrict__ sidx, int* __restrict__ cnts,
    int* __restrict__ tidx, int* __restrict__ cntt,
    float* __restrict__ out)
{
    const int w    = threadIdx.x >> 6;
    const int lane = threadIdx.x & 63;

    if (blockIdx.x >= 3072) {                    // ---- compaction tail ----
        const int row48 = (blockIdx.x - 3072) * 4 + w;   // 0..47
        const bool isq = row48 < BQ;
        const int* m = isq ? q_mask + row48 * SEQ : k_mask + (row48 - BQ) * SEQ;
        int* idx     = isq ? sidx + row48 * SEQ  : tidx + (row48 - BQ) * SEQ;
        int base = 0, first = -1;
#pragma unroll
        for (int c = 0; c < 4; ++c) {
            int v = (m[c * 64 + lane] != 0);
            unsigned long long b = __ballot(v);
            int pre = __popcll(b & ((1ull << lane) - 1ull));
            if (v) idx[base + pre] = c * 64 + lane;
            if (first < 0 && b) first = c * 64 + (int)__ffsll((unsigned long long)b) - 1;
            base += (int)__popcll(b);
        }
        const int pad = (first < 0) ? 0 : first;          // valid row (or moot)
        for (int p = base + lane; p < SEQ; p += 64) idx[p] = pad;
        if (lane == 0) { if (isq) cnts[row48] = base; else cntt[row48 - BQ] = base; }
        return;
    }

    if (blockIdx.x == 0 && threadIdx.x < 256) {  // zero out for li's atomics
        out[threadIdx.x] = 0.f; out[threadIdx.x + 256] = 0.f;
    }
    int row  = blockIdx.x * 4 + w;
    const int NQ = BQ * SEQ;
    const int mv = (row < NQ) ? q_mask[row] : k_mask[row - NQ];
    if (mv == 0) return;                         // masked row: never read by li

    const float* src = (row < NQ) ? q + (size_t)row * HD
                                  : k + (size_t)(row - NQ) * HD;
    unsigned int* dst = (unsigned int*)((row < NQ) ? qn + (size_t)row * HD
                                                   : kn + (size_t)(row - NQ) * HD);
    float4 v[3];
    float ss = 0.f;
#pragma unroll
    for (int c = 0; c < 3; ++c) {
        v[c] = ((const float4*)src)[lane + 64 * c];
        ss += v[c].x * v[c].x + v[c].y * v[c].y + v[c].z * v[c].z + v[c].w * v[c].w;
    }
#pragma unroll
    for (int m = 1; m < 64; m <<= 1) ss += __shfl_xor(ss, m, 64);
    float inv = rsqrtf(fmaxf(ss, 1e-24f));
#pragma unroll
    for (int c = 0; c < 3; ++c) {
        uint2 o = make_uint2(pack2_bf16(v[c].x * inv, v[c].y * inv),
                             pack2_bf16(v[c].z * inv, v[c].w * inv));
        ((uint2*)dst)[lane + 64 * c] = o;
    }
}

// ---------------- Phase 2: block = (j, i, s-chunk), 128 compact-s x 256 t --
// r12's proven kernel (47.6 us) + ONE wave-uniform extension: wact also
// requires wsd*64 < csrem (wsd=1 waves idle when s-chunk has <=64 valid rows;
// ~32% of active blocks). Same gate style as the proven ntg gate -- no
// branches inside the fragment/MFMA path (r11 lesson).
__global__ __launch_bounds__(512, 2) void li_kernel(
    const unsigned short* __restrict__ qn, const unsigned short* __restrict__ kn,
    const float* __restrict__ g_ls, const float* __restrict__ g_ar,
    const int* __restrict__ sidx, const int* __restrict__ cnts,
    const int* __restrict__ tidx, const int* __restrict__ cntt,
    float* __restrict__ out)
{
    const int j  = blockIdx.x, i = blockIdx.y, chs = blockIdx.z;
    const int cs = cnts[i], ct = cntt[j];
    if (chs * 128 >= cs || ct == 0) return;   // block-uniform exit
    int csrem = cs - chs * 128; if (csrem > 128) csrem = 128;
    const int ntg = (ct + 63) >> 6;           // active t-groups, 1..4
    const bool stA1 = (csrem > 64);           // block-uniform A-group-1 gate

    const int tid  = threadIdx.x;
    const int w    = tid >> 6, lane = tid & 63;
    const int ln   = lane & 15, lg = lane >> 4;
    const int wsd  = w >> 2, wt = w & 3;      // wave = (s-half, t-quarter)

    __shared__ __align__(16) unsigned short As[128 * 64];  // 16 KB, swizzled
    __shared__ __align__(16) unsigned short Bs[256 * 64];  // 32 KB, swizzled
    __shared__ float w2[SEQ];      // scale * exp(-alpha*d) * log2(e)
    __shared__ int   sor[128], tor[SEQ];     // original s/t of compact slots
    __shared__ float red[8];

    float a0 = g_ar[0];
    float alpha = (a0 > 0.f) ? a0 : 0.01f * a0;            // leaky_relu
    float scale = __expf(g_ls[0]) * 1.4426950408889634f;   // fold log2(e)
    if (tid < 256) {
        w2[tid]  = scale * __expf(-alpha * (float)tid);
        tor[tid] = tidx[j * SEQ + tid];
    } else if (tid < 384) {
        sor[tid - 256] = sidx[i * SEQ + chs * 128 + (tid - 256)];
    }

    // glds staging (r0 involution): lane covers row (base + lane>>3),
    // LDS chunk slot (lane&7), pre-swizzled source chunk (lane&7)^(row&7).
    const int rl  = lane >> 3;
    const int gch = (lane & 7) ^ rl;
    const int ia0 = sidx[i * SEQ + chs * 128 + w * 8 + rl];        // A rows 0..63
    const int ia1 = sidx[i * SEQ + chs * 128 + 64 + w * 8 + rl];   // A rows 64..127
    int ib[4];
#pragma unroll
    for (int c = 0; c < 4; ++c)
        ib[c] = tidx[j * SEQ + c * 64 + w * 8 + rl];               // B rows c*64+..
    const unsigned short* qb = qn + (size_t)i * SEQ * HD + gch * 8;
    const unsigned short* kb = kn + (size_t)j * SEQ * HD + gch * 8;
    unsigned short* al = As + (w * 8) * 64;
    unsigned short* bl = Bs + (w * 8) * 64;

    f32x4 acc[4][4];
    const f32x4 zero4 = {0.f, 0.f, 0.f, 0.f};
#pragma unroll
    for (int a = 0; a < 4; ++a)
#pragma unroll
        for (int b = 0; b < 4; ++b) acc[a][b] = zero4;

    // wave-uniform activity: t-group AND s-half must be in range
    const bool wact = (wt < ntg) && (wsd * 64 < csrem);

    for (int kk = 0; kk < HD; kk += 64) {
        __syncthreads();                       // prev stage consumed
        glds16(qb + (size_t)ia0 * HD + kk, al);
        if (stA1) glds16(qb + (size_t)ia1 * HD + kk, al + 64 * 64);
#pragma unroll
        for (int c = 0; c < 4; ++c)            // only active t-groups staged
            if (c < ntg) glds16(kb + (size_t)ib[c] * HD + kk, bl + c * (64 * 64));
        __syncthreads();                       // vmcnt drained before barrier
        if (wact) {
            const bf16x8* A8 = (const bf16x8*)As;
            const bf16x8* B8 = (const bf16x8*)Bs;
#pragma unroll
            for (int ks = 0; ks < 2; ++ks) {
                const int ch = (ks * 4 + lg) ^ (ln & 7);   // unswizzle
                bf16x8 af[4], bfr[4];
#pragma unroll
                for (int rm = 0; rm < 4; ++rm)
                    af[rm] = A8[(wsd * 64 + rm * 16 + ln) * 8 + ch];
#pragma unroll
                for (int cn = 0; cn < 4; ++cn)
                    bfr[cn] = B8[(wt * 64 + cn * 16 + ln) * 8 + ch];
#pragma unroll
                for (int rm = 0; rm < 4; ++rm)
#pragma unroll
                    for (int cn = 0; cn < 4; ++cn)
                        acc[rm][cn] = __builtin_amdgcn_mfma_f32_16x16x32_bf16(
                            af[rm], bfr[cn], acc[rm][cn], 0, 0, 0);
            }
        }
    }

    // ---------------- slim epilogue (r10) ----------------------------------
    __syncthreads();                    // all MFMA LDS reads done; reuse Bs
    float* zs  = (float*)Bs;            // [16][133] Z partials
    float* wsc = zs + 16 * 133;         // [16][133] W partials

    int   to[4];
    float kv[4];
#pragma unroll
    for (int cn = 0; cn < 4; ++cn) {
        int slot = wt * 64 + cn * 16 + ln;
        to[cn] = tor[slot];
        kv[cn] = (slot < ct) ? 1.f : 0.f;
    }

#pragma unroll
    for (int rm = 0; rm < 4; ++rm)
#pragma unroll
        for (int r = 0; r < 4; ++r) {
            int srow = wsd * 64 + rm * 16 + lg * 4 + r;   // compact s 0..127
            float ze = 0.f, we = 0.f;
            if (wact) {
                int so = sor[srow];
#pragma unroll
                for (int cn = 0; cn < 4; ++cn) {
                    float sim = acc[rm][cn][r];
                    int d = so - to[cn]; d = (d < 0) ? -d : d;
                    float e = kv[cn] * __builtin_exp2f(sim * w2[d]);
                    ze += e;
                    we = fmaf(e, sim, we);
                }
            }
            ze += __shfl_xor(ze, 1, 64);  we += __shfl_xor(we, 1, 64);
            ze += __shfl_xor(ze, 2, 64);  we += __shfl_xor(we, 2, 64);
            if ((ln & 3) == 0) {
                int zrow = wt * 4 + (ln >> 2);            // 0..15
                zs [zrow * 133 + srow] = ze;
                wsc[zrow * 133 + srow] = we;
            }
        }
    __syncthreads();

    float part = 0.f;
    if (tid < 128) {
        float Z = 0.f, W = 0.f;
#pragma unroll
        for (int c = 0; c < 16; ++c) {
            Z += zs [c * 133 + tid];
            W += wsc[c * 133 + tid];
        }
        float pt = (Z > 0.f) ? (W / Z) : 0.f;
        part = (chs * 128 + tid < cs) ? pt : 0.f;   // q-mask == slot validity
    }
#pragma unroll
    for (int m = 1; m < 64; m <<= 1) part += __shfl_xor(part, m, 64);
    if (lane == 0) red[w] = part;
    __syncthreads();
    if (tid == 0) {
        float tot = red[0] + red[1] + red[2] + red[3]
                  + red[4] + red[5] + red[6] + red[7];
        atomicAdd(&out[i * BK2 + j], tot);
    }
}

extern "C" void kernel_launch(void* const* d_in, const int* in_sizes, int n_in,
                              void* d_out, int out_size, void* d_ws, size_t ws_size,
                              hipStream_t stream) {
    const float* q  = (const float*)d_in[0];   // [16,256,768] f32
    const float* k  = (const float*)d_in[1];   // [32,256,768] f32
    const float* ls = (const float*)d_in[2];   // scalar
    const float* ar = (const float*)d_in[3];   // scalar
    const int* qm   = (const int*)d_in[4];     // [16,256]
    const int* km   = (const int*)d_in[5];     // [32,256]
    float* out      = (float*)d_out;           // [16,32] f32

    unsigned short* qn = (unsigned short*)d_ws;            // 16*256*768 bf16
    unsigned short* kn = qn + (size_t)BQ * SEQ * HD;       // 32*256*768 bf16
    int* sidx = (int*)(kn + (size_t)BK2 * SEQ * HD);       // [16][256]
    int* cnts = sidx + BQ * SEQ;                           // [16]
    int* tidx = cnts + BQ;                                 // [32][256]
    int* cntt = tidx + BK2 * SEQ;                          // [32]

    norm_kernel<<<(BQ + BK2) * SEQ / 4 + 12, 256, 0, stream>>>(
        q, k, qn, kn, qm, km, sidx, cnts, tidx, cntt, (float*)d_out);
    li_kernel<<<dim3(BK2, BQ, 2), 512, 0, stream>>>(qn, kn, ls, ar,
                                                    sidx, cnts, tidx, cntt,
                                                    (float*)d_out);
}